// Round 15
// baseline (740.828 us; speedup 1.0000x reference)
//
#include <hip/hip_runtime.h>
#include <hip/hip_bf16.h>
#include <math.h>

typedef __attribute__((ext_vector_type(8))) short bf16x8;
typedef __attribute__((ext_vector_type(4))) float f32x4;

// ---------- bf16 helpers ----------
__device__ __forceinline__ float bflo(unsigned u) { return __uint_as_float(u << 16); }
__device__ __forceinline__ float bfhi(unsigned u) { return __uint_as_float(u & 0xffff0000u); }
__device__ __forceinline__ unsigned packbf(float a, float b) {
    unsigned ua = __float_as_uint(a), ub = __float_as_uint(b);
    ua += 0x7fffu + ((ua >> 16) & 1u);
    ub += 0x7fffu + ((ub >> 16) & 1u);
    return (ua >> 16) | (ub & 0xffff0000u);
}
__device__ __forceinline__ float fsig(float w) {
    return __builtin_amdgcn_rcpf(1.f + __expf(-w));
}
__device__ __forceinline__ float silu(float g) { return g * fsig(g); }

// ---------- setup ----------
__global__ void zero_int_kernel(int* __restrict__ p, int n) {
    int i = blockIdx.x * blockDim.x + threadIdx.x;
    int s = gridDim.x * blockDim.x;
    for (; i < n; i += s) p[i] = 0;
}

__global__ void count_kernel(const int* __restrict__ dst, int* __restrict__ cnt, int E) {
    int e = blockIdx.x * blockDim.x + threadIdx.x;
    if (e < E) atomicAdd(&cnt[dst[e]], 1);
}

__global__ __launch_bounds__(1024)
void scan_block_kernel(const int* __restrict__ cnt, int* __restrict__ off,
                       int* __restrict__ bsum, int n) {
    __shared__ int wsum[16];
    int tid = threadIdx.x, lane = tid & 63, wid = tid >> 6;
    int i = blockIdx.x * 1024 + tid;
    int v = (i < n) ? cnt[i] : 0;
    int sc = v;
    #pragma unroll
    for (int s = 1; s < 64; s <<= 1) {
        int t = __shfl_up(sc, (unsigned)s, 64);
        if (lane >= s) sc += t;
    }
    if (lane == 63) wsum[wid] = sc;
    __syncthreads();
    int woff = 0;
    for (int k = 0; k < wid; k++) woff += wsum[k];
    if (i < n) off[i + 1] = woff + sc;
    if (tid == 0) {
        int t = 0;
        #pragma unroll
        for (int k = 0; k < 16; k++) t += wsum[k];
        bsum[blockIdx.x] = t;
    }
}

__global__ void scan_tops_kernel(int* __restrict__ bsum, int nb) {
    int lane = threadIdx.x;
    int v = (lane < nb) ? bsum[lane] : 0;
    int sc = v;
    #pragma unroll
    for (int s = 1; s < 64; s <<= 1) {
        int t = __shfl_up(sc, (unsigned)s, 64);
        if (lane >= s) sc += t;
    }
    if (lane < nb) bsum[lane] = sc - v;
}

__global__ __launch_bounds__(1024)
void scan_add_kernel(int* __restrict__ off, const int* __restrict__ bsum, int n) {
    int i = blockIdx.x * 1024 + threadIdx.x;
    int b = bsum[blockIdx.x];
    if (i < n) off[i + 1] += b;
    if (i == 0) off[0] = 0;
}

__global__ void fill_csr_kernel(const int* __restrict__ dst, const int* __restrict__ src,
                                const int* __restrict__ off, int* __restrict__ cnt,
                                int* __restrict__ eidx, int* __restrict__ dstc,
                                int* __restrict__ srcc, int E) {
    int e = blockIdx.x * blockDim.x + threadIdx.x;
    if (e < E) {
        int d = dst[e];
        int pos = atomicSub(&cnt[d], 1) - 1;
        int slot = off[d] + pos;
        eidx[slot] = e;
        dstc[slot] = d;
        srcc[slot] = src[e];
    }
}

// ---------- pack weights into MFMA A-operand fragments (W^T, bf16) ----------
__global__ void pack_kernel(const float* __restrict__ v_w, const float* __restrict__ e_w,
                            short* __restrict__ vwp, short* __restrict__ ewp, int L) {
    int t = blockIdx.x * blockDim.x + threadIdx.x;
    if (t >= L * 5 * 4 * 2 * 64) return;
    int lane = t & 63;
    int ks = (t >> 6) & 1;
    int ft = (t >> 7) & 3;
    int mat = t >> 9;
    int layer = mat / 5, mi = mat % 5;
    const float* W = (mi < 4) ? (v_w + (long long)(layer * 4 + mi) * 4096)
                              : (e_w + (long long)layer * 4096);
    int m = ft * 16 + (lane & 15);
    int k0 = ks * 32 + (lane >> 4) * 8;
    short* dstp = (mi < 4)
        ? vwp + ((((long long)(layer * 4 + mi) * 4 + ft) * 2 + ks) * 64 + lane) * 8
        : ewp + ((((long long)layer * 4 + ft) * 2 + ks) * 64 + lane) * 8;
    #pragma unroll
    for (int j = 0; j < 8; j++) {
        unsigned u = __float_as_uint(W[(k0 + j) * 64 + m]);
        u += 0x7fffu + ((u >> 16) & 1u);
        dstp[j] = (short)(u >> 16);
    }
}

// ---------- node GEMM (MFMA) + optional fused residual-apply of previous layer ----------
template <bool APPLY>
__global__ __launch_bounds__(256)
void node_gemm_mfma(const float* __restrict__ Xold, const float* __restrict__ h_v,
                    float* __restrict__ out_x, const float* __restrict__ fin,
                    const short* __restrict__ vwp, const float* __restrict__ vb,
                    __hip_bfloat16* __restrict__ xp, int Nn) {
    __shared__ short Xs[64 * 64];
    __shared__ short Hs[64 * 64];
    int tid = threadIdx.x;
    long long row0 = (long long)blockIdx.x * 64;

    {
        int r = tid >> 2, cq = tid & 3;
        long long row = row0 + r;
        float xv[16];
        #pragma unroll
        for (int j = 0; j < 16; j++) xv[j] = 0.f;
        if (row < Nn) {
            const float* sp = Xold + row * 64 + cq * 16;
            #pragma unroll
            for (int j = 0; j < 4; j++) {
                float4 v = *(const float4*)(sp + j * 4);
                xv[j*4] = v.x; xv[j*4+1] = v.y; xv[j*4+2] = v.z; xv[j*4+3] = v.w;
            }
            if (APPLY) {
                const float* hp = h_v + row * 64 + cq * 16;
                const float* kmp = fin + cq * 16;
                const float* kap = fin + 64 + cq * 16;
                #pragma unroll
                for (int j = 0; j < 16; j++) {
                    float g = hp[j] * kmp[j] + kap[j];
                    xv[j] = xv[j] + silu(g);
                }
                float* op = out_x + row * 64 + cq * 16;
                #pragma unroll
                for (int j = 0; j < 4; j++)
                    *(float4*)(op + j * 4) = make_float4(xv[j*4], xv[j*4+1], xv[j*4+2], xv[j*4+3]);
            }
        }
        uint4 w0, w1;
        w0.x = packbf(xv[0], xv[1]);   w0.y = packbf(xv[2], xv[3]);
        w0.z = packbf(xv[4], xv[5]);   w0.w = packbf(xv[6], xv[7]);
        w1.x = packbf(xv[8], xv[9]);   w1.y = packbf(xv[10], xv[11]);
        w1.z = packbf(xv[12], xv[13]); w1.w = packbf(xv[14], xv[15]);
        int base = r * 128 + cq * 32, swz = (r & 7) << 4;
        *(uint4*)((char*)Xs + (base ^ swz)) = w0;
        *(uint4*)((char*)Xs + ((base + 16) ^ swz)) = w1;
    }
    __syncthreads();

    int l = tid & 63;
    int rl = (tid >> 6) * 16 + (l & 15);
    bf16x8 bfr[2];
    #pragma unroll
    for (int ks = 0; ks < 2; ks++) {
        int off = (rl * 128 + ks * 64 + (l >> 4) * 16) ^ ((rl & 7) << 4);
        bfr[ks] = *(bf16x8*)((char*)Xs + off);
    }
    int q4 = (l >> 4) * 4;
    int r = tid >> 2, cc = (tid & 3) * 16;
    long long node = row0 + r;
    int swz = (r & 7) << 4;
    for (int g = 0; g < 4; g++) {
        #pragma unroll
        for (int ft = 0; ft < 4; ft++) {
            f32x4 acc = f32x4{0.f, 0.f, 0.f, 0.f};
            #pragma unroll
            for (int ks = 0; ks < 2; ks++) {
                bf16x8 a = *(const bf16x8*)(vwp + (((long long)(g * 4 + ft) * 2 + ks) * 64 + l) * 8);
                acc = __builtin_amdgcn_mfma_f32_16x16x32_bf16(a, bfr[ks], acc, 0, 0, 0);
            }
            int f0 = ft * 16 + q4;
            float4 bv = *(const float4*)&vb[g * 64 + f0];
            uint2 o;
            o.x = packbf(acc[0] + bv.x, acc[1] + bv.y);
            o.y = packbf(acc[2] + bv.z, acc[3] + bv.w);
            int hoff = (rl * 128 + f0 * 2) ^ ((rl & 7) << 4);
            *(uint2*)((char*)Hs + hoff) = o;
        }
        __syncthreads();
        if (node < Nn) {
            uint4 a = *(uint4*)((char*)Hs + ((r * 128 + cc * 2) ^ swz));
            uint4 b = *(uint4*)((char*)Hs + ((r * 128 + cc * 2 + 16) ^ swz));
            __hip_bfloat16* op = xp + ((long long)g * Nn + node) * 64 + cc;
            *(uint4*)op = a;
            *(uint4*)(op + 8) = b;
        }
        __syncthreads();
    }
}

// ---------- edge GEMM (MFMA), CSR state, fused w-update + h recompute + AGGREGATION ----------
// After stats: msg = fsig(w(l)) * x2[src] into Hs (bf16), then block-local segmented
// reduction over CSR (dst-sorted) rows: interior segments plain-store complete sums
// to acc[node]; first/last segments atomicAdd (may span blocks).
template <bool FIRST, bool LAST>
__global__ __launch_bounds__(256)
void edge_gemm_mfma(const float* __restrict__ ea, const int* __restrict__ eidx,
                    __hip_bfloat16* __restrict__ w_csr, __hip_bfloat16* __restrict__ h_e,
                    const float* __restrict__ fin,
                    const short* __restrict__ ewp_p, const float* __restrict__ eb_p,
                    const short* __restrict__ ewp, const float* __restrict__ eb,
                    const __hip_bfloat16* __restrict__ x3p, const __hip_bfloat16* __restrict__ x4p,
                    const __hip_bfloat16* __restrict__ x3, const __hip_bfloat16* __restrict__ x4,
                    const __hip_bfloat16* __restrict__ x2,
                    const int* __restrict__ dstc, const int* __restrict__ srcc,
                    float* __restrict__ estats, float* __restrict__ acc_buf) {
    __shared__ short Ws[64 * 64];
    __shared__ short Hs[64 * 68];
    __shared__ float sredS[4][64], sredQ[4][64];
    __shared__ int dstl[64], srcl[64];
    __shared__ int segstart[65];
    __shared__ int nsegS;
    int tid = threadIdx.x;
    long long row0 = (long long)blockIdx.x * 64;

    // ---- stage w tile -> Ws + segment boundaries ----
    {
        int r = tid >> 2, cq = tid & 3;
        long long grow = (row0 + r) * 64 + cq * 16;
        int base = r * 128 + cq * 32, swz = (r & 7) << 4;
        uint4 w0u, w1u;
        if (FIRST) {
            long long e0 = eidx[row0 + r];
            const float* sp = ea + e0 * 64 + cq * 16;
            float4 v0 = *(const float4*)(sp),     v1 = *(const float4*)(sp + 4);
            float4 v2 = *(const float4*)(sp + 8), v3 = *(const float4*)(sp + 12);
            w0u.x = packbf(v0.x, v0.y); w0u.y = packbf(v0.z, v0.w);
            w0u.z = packbf(v1.x, v1.y); w0u.w = packbf(v1.z, v1.w);
            w1u.x = packbf(v2.x, v2.y); w1u.y = packbf(v2.z, v2.w);
            w1u.z = packbf(v3.x, v3.y); w1u.w = packbf(v3.z, v3.w);
            *(uint4*)&w_csr[grow] = w0u;
            *(uint4*)&w_csr[grow + 8] = w1u;
        } else {
            w0u = *(const uint4*)&w_csr[grow];
            w1u = *(const uint4*)&w_csr[grow + 8];
        }
        *(uint4*)((char*)Ws + (base ^ swz)) = w0u;
        *(uint4*)((char*)Ws + ((base + 16) ^ swz)) = w1u;
        if (tid < 64) {
            int d = dstc[row0 + tid];
            dstl[tid] = d;
            srcl[tid] = srcc[row0 + tid];
            int dp = __shfl_up(d, 1, 64);
            bool flag = (tid == 0) || (d != dp);
            unsigned long long m = __ballot(flag);
            int s = (int)__popcll(m & ((2ull << tid) - 1)) - 1;
            if (flag) segstart[s] = tid;
            if (tid == 63) {
                int ns = (int)__popcll(m);
                nsegS = ns;
                segstart[ns] = 64;
            }
        }
    }
    __syncthreads();

    int l = tid & 63, wv = tid >> 6;
    int rl = wv * 16 + (l & 15);
    int q4 = (l >> 4) * 4;
    int rr0 = tid >> 3, rr1 = rr0 + 32;
    int c8 = (tid & 7) * 8;
    int de0 = dstl[rr0], se0 = srcl[rr0];
    int de1 = dstl[rr1], se1 = srcl[rr1];

    if (!FIRST) {
        uint4 p3a = *(const uint4*)&x3p[(long long)de0 * 64 + c8];
        uint4 p4a = *(const uint4*)&x4p[(long long)se0 * 64 + c8];
        uint4 p3b = *(const uint4*)&x3p[(long long)de1 * 64 + c8];
        uint4 p4b = *(const uint4*)&x4p[(long long)se1 * 64 + c8];

        bf16x8 bfr[2];
        #pragma unroll
        for (int ks = 0; ks < 2; ks++) {
            int off = (rl * 128 + ks * 64 + (l >> 4) * 16) ^ ((rl & 7) << 4);
            bfr[ks] = *(bf16x8*)((char*)Ws + off);
        }
        #pragma unroll
        for (int ft = 0; ft < 4; ft++) {
            f32x4 acc = f32x4{0.f, 0.f, 0.f, 0.f};
            #pragma unroll
            for (int ks = 0; ks < 2; ks++) {
                bf16x8 a = *(const bf16x8*)(ewp_p + (((long long)ft * 2 + ks) * 64 + l) * 8);
                acc = __builtin_amdgcn_mfma_f32_16x16x32_bf16(a, bfr[ks], acc, 0, 0, 0);
            }
            int f0 = ft * 16 + q4;
            float4 bv = *(const float4*)&eb_p[f0];
            uint2 o;
            o.x = packbf(acc[0] + bv.x, acc[1] + bv.y);
            o.y = packbf(acc[2] + bv.z, acc[3] + bv.w);
            *(uint2*)&Hs[rl * 68 + f0] = o;
        }
        __syncthreads();

        float4 km0 = *(const float4*)&fin[128 + c8], km1 = *(const float4*)&fin[128 + c8 + 4];
        float4 ka0 = *(const float4*)&fin[192 + c8], ka1 = *(const float4*)&fin[192 + c8 + 4];
        float kmv[8] = {km0.x, km0.y, km0.z, km0.w, km1.x, km1.y, km1.z, km1.w};
        float kav[8] = {ka0.x, ka0.y, ka0.z, ka0.w, ka1.x, ka1.y, ka1.z, ka1.w};
        #pragma unroll
        for (int p = 0; p < 2; p++) {
            int rr = p ? rr1 : rr0;
            uint4 p3 = p ? p3b : p3a;
            uint4 p4 = p ? p4b : p4a;
            unsigned u3[4] = {p3.x, p3.y, p3.z, p3.w};
            unsigned u4[4] = {p4.x, p4.y, p4.z, p4.w};
            uint4 hu = *(uint4*)&Hs[rr * 68 + c8];
            unsigned uh[4] = {hu.x, hu.y, hu.z, hu.w};
            int woff = (rr * 128 + c8 * 2) ^ ((rr & 7) << 4);
            uint4 wu = *(uint4*)((char*)Ws + woff);
            unsigned uw[4] = {wu.x, wu.y, wu.z, wu.w};
            float wn[8];
            #pragma unroll
            for (int j = 0; j < 4; j++) {
                float h0 = bflo(uh[j]) + bflo(u3[j]) + bflo(u4[j]);
                float h1 = bfhi(uh[j]) + bfhi(u3[j]) + bfhi(u4[j]);
                wn[2*j]   = bflo(uw[j]) + silu(h0 * kmv[2*j]   + kav[2*j]);
                wn[2*j+1] = bfhi(uw[j]) + silu(h1 * kmv[2*j+1] + kav[2*j+1]);
            }
            uint4 wo;
            wo.x = packbf(wn[0], wn[1]); wo.y = packbf(wn[2], wn[3]);
            wo.z = packbf(wn[4], wn[5]); wo.w = packbf(wn[6], wn[7]);
            *(uint4*)((char*)Ws + woff) = wo;
            *(uint4*)&w_csr[(row0 + rr) * 64 + c8] = wo;
        }
        __syncthreads();
    }

    // ---- current layer: gathers + fragment loads + MFMA ----
    uint4 g3a = *(const uint4*)&x3[(long long)de0 * 64 + c8];
    uint4 g4a = *(const uint4*)&x4[(long long)se0 * 64 + c8];
    uint4 g3b = *(const uint4*)&x3[(long long)de1 * 64 + c8];
    uint4 g4b = *(const uint4*)&x4[(long long)se1 * 64 + c8];
    uint4 g2a = *(const uint4*)&x2[(long long)se0 * 64 + c8];
    uint4 g2b = *(const uint4*)&x2[(long long)se1 * 64 + c8];
    bf16x8 bfr[2];
    #pragma unroll
    for (int ks = 0; ks < 2; ks++) {
        int off = (rl * 128 + ks * 64 + (l >> 4) * 16) ^ ((rl & 7) << 4);
        bfr[ks] = *(bf16x8*)((char*)Ws + off);
    }
    #pragma unroll
    for (int ft = 0; ft < 4; ft++) {
        f32x4 acc = f32x4{0.f, 0.f, 0.f, 0.f};
        #pragma unroll
        for (int ks = 0; ks < 2; ks++) {
            bf16x8 a = *(const bf16x8*)(ewp + (((long long)ft * 2 + ks) * 64 + l) * 8);
            acc = __builtin_amdgcn_mfma_f32_16x16x32_bf16(a, bfr[ks], acc, 0, 0, 0);
        }
        int f0 = ft * 16 + q4;
        float4 bv = *(const float4*)&eb[f0];
        uint2 o;
        o.x = packbf(acc[0] + bv.x, acc[1] + bv.y);
        o.y = packbf(acc[2] + bv.z, acc[3] + bv.w);
        *(uint2*)&Hs[rl * 68 + f0] = o;
    }
    __syncthreads();

    // ---- row-sliced epilogue: stats (+ h_e write if LAST) ----
    float s[8], q[8];
    #pragma unroll
    for (int j = 0; j < 8; j++) { s[j] = 0.f; q[j] = 0.f; }
    #pragma unroll
    for (int p = 0; p < 2; p++) {
        int rr = p ? rr1 : rr0;
        uint4 g3 = p ? g3b : g3a;
        uint4 g4 = p ? g4b : g4a;
        unsigned u3[4] = {g3.x, g3.y, g3.z, g3.w};
        unsigned u4[4] = {g4.x, g4.y, g4.z, g4.w};
        uint4 hu = *(uint4*)&Hs[rr * 68 + c8];
        unsigned uh[4] = {hu.x, hu.y, hu.z, hu.w};
        float h[8];
        #pragma unroll
        for (int j = 0; j < 4; j++) {
            float h0 = bflo(uh[j]) + bflo(u3[j]) + bflo(u4[j]);
            float h1 = bfhi(uh[j]) + bfhi(u3[j]) + bfhi(u4[j]);
            h[2*j] = h0; h[2*j+1] = h1;
            s[2*j] += h0; s[2*j+1] += h1;
            q[2*j] += h0 * h0; q[2*j+1] += h1 * h1;
        }
        if (LAST) {
            uint4 hv;
            hv.x = packbf(h[0], h[1]); hv.y = packbf(h[2], h[3]);
            hv.z = packbf(h[4], h[5]); hv.w = packbf(h[6], h[7]);
            *(uint4*)&h_e[(row0 + rr) * 64 + c8] = hv;
        }
    }
    #pragma unroll
    for (int d = 8; d < 64; d <<= 1) {
        #pragma unroll
        for (int j = 0; j < 8; j++) {
            s[j] += __shfl_xor(s[j], d);
            q[j] += __shfl_xor(q[j], d);
        }
    }
    if ((l >> 3) == 0) {
        #pragma unroll
        for (int j = 0; j < 8; j++) {
            sredS[wv][(l & 7) * 8 + j] = s[j];
            sredQ[wv][(l & 7) * 8 + j] = q[j];
        }
    }
    __syncthreads();     // all Hs reads done; sred ready
    if (tid < 128) {
        int which = tid >> 6, f = tid & 63;
        float v = which ? (sredQ[0][f] + sredQ[1][f] + sredQ[2][f] + sredQ[3][f])
                        : (sredS[0][f] + sredS[1][f] + sredS[2][f] + sredS[3][f]);
        atomicAdd(&estats[(blockIdx.x & 7) * 128 + which * 64 + f], v);
    }

    // ---- msg phase: overwrite Hs with msg = fsig(w(l)) * x2[src] (bf16) ----
    #pragma unroll
    for (int p = 0; p < 2; p++) {
        int rr = p ? rr1 : rr0;
        uint4 g2 = p ? g2b : g2a;
        unsigned u2[4] = {g2.x, g2.y, g2.z, g2.w};
        int woff = (rr * 128 + c8 * 2) ^ ((rr & 7) << 4);
        uint4 wu = *(uint4*)((char*)Ws + woff);
        unsigned uw[4] = {wu.x, wu.y, wu.z, wu.w};
        uint4 mo;
        unsigned* mop = (unsigned*)&mo;
        #pragma unroll
        for (int j = 0; j < 4; j++) {
            float m0 = bflo(u2[j]) * fsig(bflo(uw[j]));
            float m1 = bfhi(u2[j]) * fsig(bfhi(uw[j]));
            mop[j] = packbf(m0, m1);
        }
        *(uint4*)&Hs[rr * 68 + c8] = mo;
    }
    __syncthreads();

    // ---- block-local segmented reduction into acc_buf ----
    {
        int fs8 = (tid & 7) * 8;
        int nseg = nsegS;
        for (int sg = tid >> 3; sg < nseg; sg += 32) {
            int a = segstart[sg], b = segstart[sg + 1];
            int node = dstl[a];
            float sm[8] = {0.f, 0.f, 0.f, 0.f, 0.f, 0.f, 0.f, 0.f};
            for (int r = a; r < b; r++) {
                uint4 mu = *(uint4*)&Hs[r * 68 + fs8];
                unsigned um[4] = {mu.x, mu.y, mu.z, mu.w};
                #pragma unroll
                for (int j = 0; j < 4; j++) {
                    sm[2*j] += bflo(um[j]);
                    sm[2*j+1] += bfhi(um[j]);
                }
            }
            float* ap = acc_buf + (long long)node * 64 + fs8;
            if (sg == 0 || sg == nseg - 1) {
                #pragma unroll
                for (int j = 0; j < 8; j++) atomicAdd(&ap[j], sm[j]);
            } else {
                *(float4*)ap       = make_float4(sm[0], sm[1], sm[2], sm[3]);
                *(float4*)(ap + 4) = make_float4(sm[4], sm[5], sm[6], sm[7]);
            }
        }
    }
}

// ---------- node mean: h = x1 + acc/deg; stats (streaming, in-place on acc) ----------
__global__ __launch_bounds__(256)
void node_mean_kernel(float* __restrict__ h_v, const __hip_bfloat16* __restrict__ x1,
                      const int* __restrict__ off, float* __restrict__ nstats, int Nn) {
    __shared__ float red[16 * 68];
    int tid = threadIdx.x;
    int nn = tid >> 4, c4 = (tid & 15) * 4;
    int n = blockIdx.x * 16 + nn;
    float h0 = 0.f, h1 = 0.f, h2 = 0.f, h3 = 0.f;
    if (n < Nn) {
        float4 a = *(float4*)&h_v[(long long)n * 64 + c4];
        float ic = 1.f / fmaxf((float)(off[n + 1] - off[n]), 1.f);
        uint2 xq = *(const uint2*)&x1[(long long)n * 64 + c4];
        h0 = bflo(xq.x) + a.x * ic;
        h1 = bfhi(xq.x) + a.y * ic;
        h2 = bflo(xq.y) + a.z * ic;
        h3 = bfhi(xq.y) + a.w * ic;
        *(float4*)&h_v[(long long)n * 64 + c4] = make_float4(h0, h1, h2, h3);
    }
    *(float4*)&red[nn * 68 + c4] = make_float4(h0, h1, h2, h3);
    __syncthreads();
    float* nst = nstats + (blockIdx.x & 7) * 128;
    if (tid < 64) {
        float s = 0.f;
        #pragma unroll
        for (int r = 0; r < 16; r++) s += red[r * 68 + tid];
        atomicAdd(&nst[tid], s);
    }
    __syncthreads();
    *(float4*)&red[nn * 68 + c4] = make_float4(h0 * h0, h1 * h1, h2 * h2, h3 * h3);
    __syncthreads();
    if (tid < 64) {
        float s = 0.f;
        #pragma unroll
        for (int r = 0; r < 16; r++) s += red[r * 68 + tid];
        atomicAdd(&nst[64 + tid], s);
    }
}

// ---------- final edge update: out_w[eidx[j]] = w_csr[j] + silu(h_e[j]*km+ka), fp32 ----------
__global__ __launch_bounds__(256)
void out_w_final_kernel(const __hip_bfloat16* __restrict__ h_e, const __hip_bfloat16* __restrict__ w_csr,
                        const int* __restrict__ eidx, float* __restrict__ out_w,
                        const float* __restrict__ fin, long long total8) {
    __shared__ float km[64], ka[64];
    if (threadIdx.x < 64) { km[threadIdx.x] = fin[128 + threadIdx.x]; ka[threadIdx.x] = fin[192 + threadIdx.x]; }
    __syncthreads();
    for (long long t = blockIdx.x * 256LL + threadIdx.x; t < total8; t += gridDim.x * 256LL) {
        long long j = t >> 3;
        int c8 = (int)(t & 7) * 8;
        uint4 hu = *(const uint4*)&h_e[j * 64 + c8];
        uint4 wu = *(const uint4*)&w_csr[j * 64 + c8];
        int e = eidx[j];
        unsigned uh[4] = {hu.x, hu.y, hu.z, hu.w};
        unsigned uw[4] = {wu.x, wu.y, wu.z, wu.w};
        float4 m0 = *(float4*)&km[c8], m1 = *(float4*)&km[c8 + 4];
        float4 a0 = *(float4*)&ka[c8], a1 = *(float4*)&ka[c8 + 4];
        float mv[8] = {m0.x, m0.y, m0.z, m0.w, m1.x, m1.y, m1.z, m1.w};
        float av[8] = {a0.x, a0.y, a0.z, a0.w, a1.x, a1.y, a1.z, a1.w};
        float o[8];
        #pragma unroll
        for (int j2 = 0; j2 < 4; j2++) {
            o[2*j2]   = bflo(uw[j2]) + silu(bflo(uh[j2]) * mv[2*j2]   + av[2*j2]);
            o[2*j2+1] = bfhi(uw[j2]) + silu(bfhi(uh[j2]) * mv[2*j2+1] + av[2*j2+1]);
        }
        float* op = out_w + (long long)e * 64 + c8;
        *(float4*)op       = make_float4(o[0], o[1], o[2], o[3]);
        *(float4*)(op + 4) = make_float4(o[4], o[5], o[6], o[7]);
    }
}

// ---------- finalize edge part ----------
__global__ void finalize_edge_kernel(const float* __restrict__ estats,
                                     const float* __restrict__ es, const float* __restrict__ eb,
                                     float* __restrict__ fin, float invE) {
    int c = threadIdx.x;
    float s = 0.f, q = 0.f;
    #pragma unroll
    for (int r = 0; r < 8; r++) { s += estats[r * 128 + c]; q += estats[r * 128 + 64 + c]; }
    float mean = s * invE;
    float var = q * invE - mean * mean;
    float kmul = rsqrtf(var + 1e-5f) * es[c];
    fin[128 + c] = kmul;
    fin[192 + c] = eb[c] - mean * kmul;
}

// ---------- finalize node part ----------
__global__ void finalize_node_kernel(const float* __restrict__ nstats,
                                     const float* __restrict__ vs, const float* __restrict__ vb,
                                     float* __restrict__ fin, float invN) {
    int c = threadIdx.x;
    float s = 0.f, q = 0.f;
    #pragma unroll
    for (int r = 0; r < 8; r++) { s += nstats[r * 128 + c]; q += nstats[r * 128 + 64 + c]; }
    float mean = s * invN;
    float var = q * invN - mean * mean;
    float kmul = rsqrtf(var + 1e-5f) * vs[c];
    fin[c] = kmul;
    fin[64 + c] = vb[c] - mean * kmul;
}

// ---------- node BN apply (standalone, last layer only) ----------
__global__ __launch_bounds__(256)
void node_apply_kernel(const float4* __restrict__ hv4, const float4* __restrict__ xold4,
                       float4* __restrict__ out4, const float* __restrict__ fin, int total) {
    __shared__ float km[64], ka[64];
    if (threadIdx.x < 64) { km[threadIdx.x] = fin[threadIdx.x]; ka[threadIdx.x] = fin[64 + threadIdx.x]; }
    __syncthreads();
    int idx = blockIdx.x * 256 + threadIdx.x;
    if (idx >= total) return;
    int c0 = (idx & 15) * 4;
    float4 h = hv4[idx], xo = xold4[idx];
    float4 m = *(float4*)&km[c0], a = *(float4*)&ka[c0];
    float g0 = h.x * m.x + a.x, g1 = h.y * m.y + a.y, g2 = h.z * m.z + a.z, g3 = h.w * m.w + a.w;
    out4[idx] = make_float4(xo.x + silu(g0), xo.y + silu(g1),
                            xo.z + silu(g2), xo.w + silu(g3));
}

// ---------- launch ----------
extern "C" void kernel_launch(void* const* d_in, const int* in_sizes, int n_in,
                              void* d_out, int out_size, void* d_ws, size_t ws_size,
                              hipStream_t stream) {
    const float* x_in  = (const float*)d_in[0];
    const float* ea_in = (const float*)d_in[1];
    const int*   ei    = (const int*)d_in[2];
    const float* v_w   = (const float*)d_in[3];
    const float* v_b   = (const float*)d_in[4];
    const float* e_w   = (const float*)d_in[5];
    const float* e_b   = (const float*)d_in[6];
    const float* vbn_s = (const float*)d_in[7];
    const float* vbn_b = (const float*)d_in[8];
    const float* ebn_s = (const float*)d_in[9];
    const float* ebn_b = (const float*)d_in[10];

    const int Nn = in_sizes[0] / 64;
    const int E  = in_sizes[1] / 64;
    const int L  = in_sizes[3] / (4 * 64 * 64);

    const int* dst = ei;
    const int* src = ei + E;

    // workspace layout
    float* h_v    = (float*)d_ws;                       // [Nn][64] fp32 (acc + h)
    float* nstats = h_v + (long long)Nn * 64;           // [L][8][128]
    float* estats = nstats + (long long)L * 1024;       // [L][8][128]
    float* fin    = estats + (long long)L * 1024;       // [4][64]
    __hip_bfloat16* xp0   = (__hip_bfloat16*)(fin + 256);      // [4][Nn][64]
    __hip_bfloat16* xp1   = xp0 + (long long)4 * Nn * 64;      // [4][Nn][64]
    __hip_bfloat16* h_e   = xp1 + (long long)4 * Nn * 64;      // [E][64] CSR (last layer only)
    __hip_bfloat16* w_csr = h_e + (long long)E * 64;           // [E][64] CSR
    short* vwp = (short*)(w_csr + (long long)E * 64);   // [L][4][4][2][64][8]
    short* ewp = vwp + (long long)L * 16384;            // [L][4][2][64][8]
    int* cnt  = (int*)(ewp + (long long)L * 4096);      // [Nn]
    int* off  = cnt + Nn;                               // [Nn+1]
    int* eidx = off + Nn + 1;                           // [E]
    int* dstc = eidx + E;                               // [E]
    int* srcc = dstc + E;                               // [E]
    int* bsum = srcc + E;                               // [64]

    size_t needed = ((size_t)Nn * 64 + (size_t)L * 2048 + 256) * 4 +
                    ((size_t)8 * Nn * 64 + (size_t)2 * E * 64 + (size_t)L * 20480) * 2 +
                    ((size_t)2 * Nn + 1 + (size_t)3 * E + 64) * 4;
    if (ws_size < needed) return;

    float* out_x = (float*)d_out;
    float* out_w = out_x + (long long)Nn * 64;

    // CSR build + zero stats + pack weights (once per call)
    const int nb = (Nn + 1023) / 1024;
    zero_int_kernel<<<64, 256, 0, stream>>>(cnt, Nn);
    zero_int_kernel<<<8, 256, 0, stream>>>((int*)nstats, L * 2048);
    count_kernel<<<(E + 255) / 256, 256, 0, stream>>>(dst, cnt, E);
    scan_block_kernel<<<nb, 1024, 0, stream>>>(cnt, off, bsum, Nn);
    scan_tops_kernel<<<1, 64, 0, stream>>>(bsum, nb);
    scan_add_kernel<<<nb, 1024, 0, stream>>>(off, bsum, Nn);
    fill_csr_kernel<<<(E + 255) / 256, 256, 0, stream>>>(dst, src, off, cnt, eidx, dstc, srcc, E);
    pack_kernel<<<(L * 2560 + 255) / 256, 256, 0, stream>>>(v_w, e_w, vwp, ewp, L);

    for (int l = 0; l < L; l++) {
        bool first = (l == 0);
        bool last = (l == L - 1);
        float* nst = nstats + (long long)l * 1024;
        float* est = estats + (long long)l * 1024;
        __hip_bfloat16* xp_cur  = (l & 1) ? xp1 : xp0;
        __hip_bfloat16* xp_prev = (l & 1) ? xp0 : xp1;
        const __hip_bfloat16* x1 = xp_cur;
        const __hip_bfloat16* x2 = xp_cur + (long long)Nn * 64;
        const __hip_bfloat16* x3 = xp_cur + (long long)2 * Nn * 64;
        const __hip_bfloat16* x4 = xp_cur + (long long)3 * Nn * 64;
        const __hip_bfloat16* x3p = xp_prev + (long long)2 * Nn * 64;
        const __hip_bfloat16* x4p = xp_prev + (long long)3 * Nn * 64;

        // node projections -> xp_cur; l>=1 fuses previous layer's residual apply
        const float* xold = (l <= 1) ? x_in : out_x;
        if (first)
            node_gemm_mfma<false><<<(Nn + 63) / 64, 256, 0, stream>>>(
                x_in, h_v, out_x, fin, vwp + (long long)l * 16384, v_b + l * 256, xp_cur, Nn);
        else
            node_gemm_mfma<true><<<(Nn + 63) / 64, 256, 0, stream>>>(
                xold, h_v, out_x, fin, vwp + (long long)l * 16384, v_b + l * 256, xp_cur, Nn);

        // zero aggregation buffer (h_v consumed by node_gemm above)
        hipMemsetAsync(h_v, 0, (size_t)Nn * 64 * 4, stream);

        // edge GEMM: stage w + (recompute h_prev + fused update) + stats + aggregation
        const short* ewp_c = ewp + (long long)l * 4096;
        const short* ewp_pv = (l > 0) ? ewp + (long long)(l - 1) * 4096 : ewp_c;
        const float* eb_c = e_b + l * 64;
        const float* eb_pv = (l > 0) ? e_b + (l - 1) * 64 : eb_c;
        if (first && !last)
            edge_gemm_mfma<true, false><<<E / 64, 256, 0, stream>>>(
                ea_in, eidx, w_csr, h_e, fin, ewp_pv, eb_pv, ewp_c, eb_c,
                x3p, x4p, x3, x4, x2, dstc, srcc, est, h_v);
        else if (first && last)
            edge_gemm_mfma<true, true><<<E / 64, 256, 0, stream>>>(
                ea_in, eidx, w_csr, h_e, fin, ewp_pv, eb_pv, ewp_c, eb_c,
                x3p, x4p, x3, x4, x2, dstc, srcc, est, h_v);
        else if (!first && !last)
            edge_gemm_mfma<false, false><<<E / 64, 256, 0, stream>>>(
                ea_in, eidx, w_csr, h_e, fin, ewp_pv, eb_pv, ewp_c, eb_c,
                x3p, x4p, x3, x4, x2, dstc, srcc, est, h_v);
        else
            edge_gemm_mfma<false, true><<<E / 64, 256, 0, stream>>>(
                ea_in, eidx, w_csr, h_e, fin, ewp_pv, eb_pv, ewp_c, eb_c,
                x3p, x4p, x3, x4, x2, dstc, srcc, est, h_v);

        // fold edge BN affine -> fin[128..256]
        finalize_edge_kernel<<<1, 64, 0, stream>>>(
            est, ebn_s + l * 64, ebn_b + l * 64, fin, 1.f / (float)E);

        // h = x1 + acc/deg; node stats (streaming, in-place)
        node_mean_kernel<<<(Nn + 15) / 16, 256, 0, stream>>>(
            h_v, x1, off, nst, Nn);

        // fold node BN affine -> fin[0..128]
        finalize_node_kernel<<<1, 64, 0, stream>>>(
            nst, vbn_s + l * 64, vbn_b + l * 64, fin, 1.f / (float)Nn);

        if (last) {
            // final edge output (needs fin edge part of this layer)
            out_w_final_kernel<<<4096, 256, 0, stream>>>(
                h_e, w_csr, eidx, out_w, fin, (long long)E * 8);
            // standalone node apply for the last layer
            const float* xo_last = (L == 1) ? x_in : out_x;
            node_apply_kernel<<<(Nn * 16 + 255) / 256, 256, 0, stream>>>(
                (const float4*)h_v, (const float4*)xo_last, (float4*)out_x, fin, Nn * 16);
        }
    }
}

// Round 16
// 645.195 us; speedup vs baseline: 1.1482x; 1.1482x over previous
//
#include <hip/hip_runtime.h>
#include <hip/hip_bf16.h>
#include <math.h>

typedef __attribute__((ext_vector_type(8))) short bf16x8;
typedef __attribute__((ext_vector_type(4))) float f32x4;

// ---------- bf16 helpers ----------
__device__ __forceinline__ float bflo(unsigned u) { return __uint_as_float(u << 16); }
__device__ __forceinline__ float bfhi(unsigned u) { return __uint_as_float(u & 0xffff0000u); }
__device__ __forceinline__ unsigned packbf(float a, float b) {
    unsigned ua = __float_as_uint(a), ub = __float_as_uint(b);
    ua += 0x7fffu + ((ua >> 16) & 1u);
    ub += 0x7fffu + ((ub >> 16) & 1u);
    return (ua >> 16) | (ub & 0xffff0000u);
}
// fast sigmoid/silu: v_rcp_f32 (~1 ulp) instead of IEEE divide
__device__ __forceinline__ float fsig(float w) {
    return __builtin_amdgcn_rcpf(1.f + __expf(-w));
}
__device__ __forceinline__ float silu(float g) { return g * fsig(g); }

// ---------- setup ----------
__global__ void zero_int_kernel(int* __restrict__ p, int n) {
    int i = blockIdx.x * blockDim.x + threadIdx.x;
    int s = gridDim.x * blockDim.x;
    for (; i < n; i += s) p[i] = 0;
}

__global__ void count_kernel(const int* __restrict__ dst, int* __restrict__ cnt, int E) {
    int e = blockIdx.x * blockDim.x + threadIdx.x;
    if (e < E) atomicAdd(&cnt[dst[e]], 1);
}

// 3-phase scan
__global__ __launch_bounds__(1024)
void scan_block_kernel(const int* __restrict__ cnt, int* __restrict__ off,
                       int* __restrict__ bsum, int n) {
    __shared__ int wsum[16];
    int tid = threadIdx.x, lane = tid & 63, wid = tid >> 6;
    int i = blockIdx.x * 1024 + tid;
    int v = (i < n) ? cnt[i] : 0;
    int sc = v;
    #pragma unroll
    for (int s = 1; s < 64; s <<= 1) {
        int t = __shfl_up(sc, (unsigned)s, 64);
        if (lane >= s) sc += t;
    }
    if (lane == 63) wsum[wid] = sc;
    __syncthreads();
    int woff = 0;
    for (int k = 0; k < wid; k++) woff += wsum[k];
    if (i < n) off[i + 1] = woff + sc;
    if (tid == 0) {
        int t = 0;
        #pragma unroll
        for (int k = 0; k < 16; k++) t += wsum[k];
        bsum[blockIdx.x] = t;
    }
}

__global__ void scan_tops_kernel(int* __restrict__ bsum, int nb) {
    int lane = threadIdx.x;
    int v = (lane < nb) ? bsum[lane] : 0;
    int sc = v;
    #pragma unroll
    for (int s = 1; s < 64; s <<= 1) {
        int t = __shfl_up(sc, (unsigned)s, 64);
        if (lane >= s) sc += t;
    }
    if (lane < nb) bsum[lane] = sc - v;
}

__global__ __launch_bounds__(1024)
void scan_add_kernel(int* __restrict__ off, const int* __restrict__ bsum, int n) {
    int i = blockIdx.x * 1024 + threadIdx.x;
    int b = bsum[blockIdx.x];
    if (i < n) off[i + 1] += b;
    if (i == 0) off[0] = 0;
}

__global__ void fill_csr_kernel(const int* __restrict__ dst, const int* __restrict__ src,
                                const int* __restrict__ off, int* __restrict__ cnt,
                                int* __restrict__ eidx, int* __restrict__ dstc,
                                int* __restrict__ srcc, int E) {
    int e = blockIdx.x * blockDim.x + threadIdx.x;
    if (e < E) {
        int d = dst[e];
        int pos = atomicSub(&cnt[d], 1) - 1;
        int slot = off[d] + pos;
        eidx[slot] = e;
        dstc[slot] = d;
        srcc[slot] = src[e];
    }
}

// ---------- pack weights into MFMA A-operand fragments (W^T, bf16) ----------
__global__ void pack_kernel(const float* __restrict__ v_w, const float* __restrict__ e_w,
                            short* __restrict__ vwp, short* __restrict__ ewp, int L) {
    int t = blockIdx.x * blockDim.x + threadIdx.x;
    if (t >= L * 5 * 4 * 2 * 64) return;
    int lane = t & 63;
    int ks = (t >> 6) & 1;
    int ft = (t >> 7) & 3;
    int mat = t >> 9;
    int layer = mat / 5, mi = mat % 5;
    const float* W = (mi < 4) ? (v_w + (long long)(layer * 4 + mi) * 4096)
                              : (e_w + (long long)layer * 4096);
    int m = ft * 16 + (lane & 15);
    int k0 = ks * 32 + (lane >> 4) * 8;
    short* dstp = (mi < 4)
        ? vwp + ((((long long)(layer * 4 + mi) * 4 + ft) * 2 + ks) * 64 + lane) * 8
        : ewp + ((((long long)layer * 4 + ft) * 2 + ks) * 64 + lane) * 8;
    #pragma unroll
    for (int j = 0; j < 8; j++) {
        unsigned u = __float_as_uint(W[(k0 + j) * 64 + m]);
        u += 0x7fffu + ((u >> 16) & 1u);
        dstp[j] = (short)(u >> 16);
    }
}

// ---------- node GEMM (MFMA) + optional fused residual-apply of previous layer ----------
template <bool APPLY>
__global__ __launch_bounds__(256)
void node_gemm_mfma(const float* __restrict__ Xold, const float* __restrict__ h_v,
                    float* __restrict__ out_x, const float* __restrict__ fin,
                    const short* __restrict__ vwp, const float* __restrict__ vb,
                    __hip_bfloat16* __restrict__ xp, int Nn) {
    __shared__ short Xs[64 * 64];
    __shared__ short Hs[64 * 64];
    int tid = threadIdx.x;
    long long row0 = (long long)blockIdx.x * 64;

    {
        int r = tid >> 2, cq = tid & 3;
        long long row = row0 + r;
        float xv[16];
        #pragma unroll
        for (int j = 0; j < 16; j++) xv[j] = 0.f;
        if (row < Nn) {
            const float* sp = Xold + row * 64 + cq * 16;
            #pragma unroll
            for (int j = 0; j < 4; j++) {
                float4 v = *(const float4*)(sp + j * 4);
                xv[j*4] = v.x; xv[j*4+1] = v.y; xv[j*4+2] = v.z; xv[j*4+3] = v.w;
            }
            if (APPLY) {
                const float* hp = h_v + row * 64 + cq * 16;
                const float* kmp = fin + cq * 16;
                const float* kap = fin + 64 + cq * 16;
                #pragma unroll
                for (int j = 0; j < 16; j++) {
                    float g = hp[j] * kmp[j] + kap[j];
                    xv[j] = xv[j] + silu(g);
                }
                float* op = out_x + row * 64 + cq * 16;
                #pragma unroll
                for (int j = 0; j < 4; j++)
                    *(float4*)(op + j * 4) = make_float4(xv[j*4], xv[j*4+1], xv[j*4+2], xv[j*4+3]);
            }
        }
        uint4 w0, w1;
        w0.x = packbf(xv[0], xv[1]);   w0.y = packbf(xv[2], xv[3]);
        w0.z = packbf(xv[4], xv[5]);   w0.w = packbf(xv[6], xv[7]);
        w1.x = packbf(xv[8], xv[9]);   w1.y = packbf(xv[10], xv[11]);
        w1.z = packbf(xv[12], xv[13]); w1.w = packbf(xv[14], xv[15]);
        int base = r * 128 + cq * 32, swz = (r & 7) << 4;
        *(uint4*)((char*)Xs + (base ^ swz)) = w0;
        *(uint4*)((char*)Xs + ((base + 16) ^ swz)) = w1;
    }
    __syncthreads();

    int l = tid & 63;
    int rl = (tid >> 6) * 16 + (l & 15);
    bf16x8 bfr[2];
    #pragma unroll
    for (int ks = 0; ks < 2; ks++) {
        int off = (rl * 128 + ks * 64 + (l >> 4) * 16) ^ ((rl & 7) << 4);
        bfr[ks] = *(bf16x8*)((char*)Xs + off);
    }
    int q4 = (l >> 4) * 4;
    int r = tid >> 2, cc = (tid & 3) * 16;
    long long node = row0 + r;
    int swz = (r & 7) << 4;
    for (int g = 0; g < 4; g++) {
        #pragma unroll
        for (int ft = 0; ft < 4; ft++) {
            f32x4 acc = f32x4{0.f, 0.f, 0.f, 0.f};
            #pragma unroll
            for (int ks = 0; ks < 2; ks++) {
                bf16x8 a = *(const bf16x8*)(vwp + (((long long)(g * 4 + ft) * 2 + ks) * 64 + l) * 8);
                acc = __builtin_amdgcn_mfma_f32_16x16x32_bf16(a, bfr[ks], acc, 0, 0, 0);
            }
            int f0 = ft * 16 + q4;
            float4 bv = *(const float4*)&vb[g * 64 + f0];
            uint2 o;
            o.x = packbf(acc[0] + bv.x, acc[1] + bv.y);
            o.y = packbf(acc[2] + bv.z, acc[3] + bv.w);
            int hoff = (rl * 128 + f0 * 2) ^ ((rl & 7) << 4);
            *(uint2*)((char*)Hs + hoff) = o;
        }
        __syncthreads();
        if (node < Nn) {
            uint4 a = *(uint4*)((char*)Hs + ((r * 128 + cc * 2) ^ swz));
            uint4 b = *(uint4*)((char*)Hs + ((r * 128 + cc * 2 + 16) ^ swz));
            __hip_bfloat16* op = xp + ((long long)g * Nn + node) * 64 + cc;
            *(uint4*)op = a;
            *(uint4*)(op + 8) = b;
        }
        __syncthreads();
    }
}

// ---------- edge GEMM (MFMA), CSR state, h_e RECOMPUTE scheme ----------
template <bool FIRST, bool LAST>
__global__ __launch_bounds__(256)
void edge_gemm_mfma(const float* __restrict__ ea, const int* __restrict__ eidx,
                    __hip_bfloat16* __restrict__ w_csr, __hip_bfloat16* __restrict__ h_e,
                    const float* __restrict__ fin,
                    const short* __restrict__ ewp_p, const float* __restrict__ eb_p,
                    const short* __restrict__ ewp, const float* __restrict__ eb,
                    const __hip_bfloat16* __restrict__ x3p, const __hip_bfloat16* __restrict__ x4p,
                    const __hip_bfloat16* __restrict__ x3, const __hip_bfloat16* __restrict__ x4,
                    const int* __restrict__ dstc, const int* __restrict__ srcc,
                    float* __restrict__ estats) {
    __shared__ short Ws[64 * 64];
    __shared__ short Hs[64 * 68];
    __shared__ float sredS[4][64], sredQ[4][64];
    __shared__ int dstl[64], srcl[64];
    int tid = threadIdx.x;
    long long row0 = (long long)blockIdx.x * 64;

    // ---- stage w tile -> Ws ----
    {
        int r = tid >> 2, cq = tid & 3;
        long long grow = (row0 + r) * 64 + cq * 16;
        int base = r * 128 + cq * 32, swz = (r & 7) << 4;
        uint4 w0u, w1u;
        if (FIRST) {
            long long e0 = eidx[row0 + r];
            const float* sp = ea + e0 * 64 + cq * 16;
            float4 v0 = *(const float4*)(sp),     v1 = *(const float4*)(sp + 4);
            float4 v2 = *(const float4*)(sp + 8), v3 = *(const float4*)(sp + 12);
            w0u.x = packbf(v0.x, v0.y); w0u.y = packbf(v0.z, v0.w);
            w0u.z = packbf(v1.x, v1.y); w0u.w = packbf(v1.z, v1.w);
            w1u.x = packbf(v2.x, v2.y); w1u.y = packbf(v2.z, v2.w);
            w1u.z = packbf(v3.x, v3.y); w1u.w = packbf(v3.z, v3.w);
            *(uint4*)&w_csr[grow] = w0u;
            *(uint4*)&w_csr[grow + 8] = w1u;
        } else {
            w0u = *(const uint4*)&w_csr[grow];
            w1u = *(const uint4*)&w_csr[grow + 8];
        }
        *(uint4*)((char*)Ws + (base ^ swz)) = w0u;
        *(uint4*)((char*)Ws + ((base + 16) ^ swz)) = w1u;
        if (tid < 64) {
            dstl[tid] = dstc[row0 + tid];
            srcl[tid] = srcc[row0 + tid];
        }
    }
    __syncthreads();

    int l = tid & 63, wv = tid >> 6;
    int rl = wv * 16 + (l & 15);
    int q4 = (l >> 4) * 4;
    int rr0 = tid >> 3, rr1 = rr0 + 32;
    int c8 = (tid & 7) * 8;
    int de0 = dstl[rr0], se0 = srcl[rr0];
    int de1 = dstl[rr1], se1 = srcl[rr1];

    if (!FIRST) {
        uint4 p3a = *(const uint4*)&x3p[(long long)de0 * 64 + c8];
        uint4 p4a = *(const uint4*)&x4p[(long long)se0 * 64 + c8];
        uint4 p3b = *(const uint4*)&x3p[(long long)de1 * 64 + c8];
        uint4 p4b = *(const uint4*)&x4p[(long long)se1 * 64 + c8];

        bf16x8 bfr[2];
        #pragma unroll
        for (int ks = 0; ks < 2; ks++) {
            int off = (rl * 128 + ks * 64 + (l >> 4) * 16) ^ ((rl & 7) << 4);
            bfr[ks] = *(bf16x8*)((char*)Ws + off);
        }
        #pragma unroll
        for (int ft = 0; ft < 4; ft++) {
            f32x4 acc = f32x4{0.f, 0.f, 0.f, 0.f};
            #pragma unroll
            for (int ks = 0; ks < 2; ks++) {
                bf16x8 a = *(const bf16x8*)(ewp_p + (((long long)ft * 2 + ks) * 64 + l) * 8);
                acc = __builtin_amdgcn_mfma_f32_16x16x32_bf16(a, bfr[ks], acc, 0, 0, 0);
            }
            int f0 = ft * 16 + q4;
            float4 bv = *(const float4*)&eb_p[f0];
            uint2 o;
            o.x = packbf(acc[0] + bv.x, acc[1] + bv.y);
            o.y = packbf(acc[2] + bv.z, acc[3] + bv.w);
            *(uint2*)&Hs[rl * 68 + f0] = o;
        }
        __syncthreads();

        float4 km0 = *(const float4*)&fin[128 + c8], km1 = *(const float4*)&fin[128 + c8 + 4];
        float4 ka0 = *(const float4*)&fin[192 + c8], ka1 = *(const float4*)&fin[192 + c8 + 4];
        float kmv[8] = {km0.x, km0.y, km0.z, km0.w, km1.x, km1.y, km1.z, km1.w};
        float kav[8] = {ka0.x, ka0.y, ka0.z, ka0.w, ka1.x, ka1.y, ka1.z, ka1.w};
        #pragma unroll
        for (int p = 0; p < 2; p++) {
            int rr = p ? rr1 : rr0;
            uint4 p3 = p ? p3b : p3a;
            uint4 p4 = p ? p4b : p4a;
            unsigned u3[4] = {p3.x, p3.y, p3.z, p3.w};
            unsigned u4[4] = {p4.x, p4.y, p4.z, p4.w};
            uint4 hu = *(uint4*)&Hs[rr * 68 + c8];
            unsigned uh[4] = {hu.x, hu.y, hu.z, hu.w};
            int woff = (rr * 128 + c8 * 2) ^ ((rr & 7) << 4);
            uint4 wu = *(uint4*)((char*)Ws + woff);
            unsigned uw[4] = {wu.x, wu.y, wu.z, wu.w};
            float wn[8];
            #pragma unroll
            for (int j = 0; j < 4; j++) {
                float h0 = bflo(uh[j]) + bflo(u3[j]) + bflo(u4[j]);
                float h1 = bfhi(uh[j]) + bfhi(u3[j]) + bfhi(u4[j]);
                wn[2*j]   = bflo(uw[j]) + silu(h0 * kmv[2*j]   + kav[2*j]);
                wn[2*j+1] = bfhi(uw[j]) + silu(h1 * kmv[2*j+1] + kav[2*j+1]);
            }
            uint4 wo;
            wo.x = packbf(wn[0], wn[1]); wo.y = packbf(wn[2], wn[3]);
            wo.z = packbf(wn[4], wn[5]); wo.w = packbf(wn[6], wn[7]);
            *(uint4*)((char*)Ws + woff) = wo;
            *(uint4*)&w_csr[(row0 + rr) * 64 + c8] = wo;
        }
        __syncthreads();
    }

    // ---- current layer: gathers + fragment loads + MFMA ----
    uint4 g3a = *(const uint4*)&x3[(long long)de0 * 64 + c8];
    uint4 g4a = *(const uint4*)&x4[(long long)se0 * 64 + c8];
    uint4 g3b = *(const uint4*)&x3[(long long)de1 * 64 + c8];
    uint4 g4b = *(const uint4*)&x4[(long long)se1 * 64 + c8];
    bf16x8 bfr[2];
    #pragma unroll
    for (int ks = 0; ks < 2; ks++) {
        int off = (rl * 128 + ks * 64 + (l >> 4) * 16) ^ ((rl & 7) << 4);
        bfr[ks] = *(bf16x8*)((char*)Ws + off);
    }
    #pragma unroll
    for (int ft = 0; ft < 4; ft++) {
        f32x4 acc = f32x4{0.f, 0.f, 0.f, 0.f};
        #pragma unroll
        for (int ks = 0; ks < 2; ks++) {
            bf16x8 a = *(const bf16x8*)(ewp + (((long long)ft * 2 + ks) * 64 + l) * 8);
            acc = __builtin_amdgcn_mfma_f32_16x16x32_bf16(a, bfr[ks], acc, 0, 0, 0);
        }
        int f0 = ft * 16 + q4;
        float4 bv = *(const float4*)&eb[f0];
        uint2 o;
        o.x = packbf(acc[0] + bv.x, acc[1] + bv.y);
        o.y = packbf(acc[2] + bv.z, acc[3] + bv.w);
        *(uint2*)&Hs[rl * 68 + f0] = o;
    }
    __syncthreads();

    // ---- row-sliced epilogue: stats (+ h_e write if LAST) ----
    float s[8], q[8];
    #pragma unroll
    for (int j = 0; j < 8; j++) { s[j] = 0.f; q[j] = 0.f; }
    #pragma unroll
    for (int p = 0; p < 2; p++) {
        int rr = p ? rr1 : rr0;
        uint4 g3 = p ? g3b : g3a;
        uint4 g4 = p ? g4b : g4a;
        unsigned u3[4] = {g3.x, g3.y, g3.z, g3.w};
        unsigned u4[4] = {g4.x, g4.y, g4.z, g4.w};
        uint4 hu = *(uint4*)&Hs[rr * 68 + c8];
        unsigned uh[4] = {hu.x, hu.y, hu.z, hu.w};
        float h[8];
        #pragma unroll
        for (int j = 0; j < 4; j++) {
            float h0 = bflo(uh[j]) + bflo(u3[j]) + bflo(u4[j]);
            float h1 = bfhi(uh[j]) + bfhi(u3[j]) + bfhi(u4[j]);
            h[2*j] = h0; h[2*j+1] = h1;
            s[2*j] += h0; s[2*j+1] += h1;
            q[2*j] += h0 * h0; q[2*j+1] += h1 * h1;
        }
        if (LAST) {
            uint4 hv;
            hv.x = packbf(h[0], h[1]); hv.y = packbf(h[2], h[3]);
            hv.z = packbf(h[4], h[5]); hv.w = packbf(h[6], h[7]);
            *(uint4*)&h_e[(row0 + rr) * 64 + c8] = hv;
        }
    }
    #pragma unroll
    for (int d = 8; d < 64; d <<= 1) {
        #pragma unroll
        for (int j = 0; j < 8; j++) {
            s[j] += __shfl_xor(s[j], d);
            q[j] += __shfl_xor(q[j], d);
        }
    }
    if ((l >> 3) == 0) {
        #pragma unroll
        for (int j = 0; j < 8; j++) {
            sredS[wv][(l & 7) * 8 + j] = s[j];
            sredQ[wv][(l & 7) * 8 + j] = q[j];
        }
    }
    __syncthreads();
    if (tid < 128) {
        int which = tid >> 6, f = tid & 63;
        float v = which ? (sredQ[0][f] + sredQ[1][f] + sredQ[2][f] + sredQ[3][f])
                        : (sredS[0][f] + sredS[1][f] + sredS[2][f] + sredS[3][f]);
        atomicAdd(&estats[(blockIdx.x & 7) * 128 + which * 64 + f], v);
    }
}

// ---------- node finish: aggregation + node stats; FINAL also emits out_w in-loop ----------
// half-wave (32 lanes) per node; 16 lanes per edge row (uint2/lane), two edges
// concurrently (sub = lane>>4), 2-pair unroll -> 4 edges in flight.
template <bool FINAL>
__global__ __launch_bounds__(256)
void node_finish_kernel(const __hip_bfloat16* __restrict__ w_csr, const int* __restrict__ srcc,
                        const __hip_bfloat16* __restrict__ x2, const __hip_bfloat16* __restrict__ x1,
                        const int* __restrict__ off, float* __restrict__ h_v,
                        float* __restrict__ nstats,
                        const __hip_bfloat16* __restrict__ h_e, const int* __restrict__ eidx,
                        float* __restrict__ out_w, const float* __restrict__ fin, int Nn) {
    __shared__ float red[8 * 68];
    __shared__ float km[64], ka[64];
    int tid = threadIdx.x;
    if (FINAL) {
        if (tid < 64) { km[tid] = fin[128 + tid]; ka[tid] = fin[192 + tid]; }
        __syncthreads();
    }
    int hw = tid >> 5;
    int lane = tid & 31;
    int sub = lane >> 4;          // which edge of the pair
    int f4 = (lane & 15) * 4;     // 4 features per lane
    int n = blockIdx.x * 8 + hw;
    float a0 = 0.f, a1 = 0.f, a2 = 0.f, a3 = 0.f;
    float h0 = 0.f, h1 = 0.f, h2 = 0.f, h3 = 0.f;
    if (n < Nn) {
        int o0 = off[n], o1 = off[n + 1];
        int j = o0;
        for (; j + 3 < o1; j += 4) {        // 2 pairs: 4 edges in flight
            long long je0 = j + sub, je1 = j + 2 + sub;
            int s0 = srcc[je0], s1 = srcc[je1];
            uint2 wq0 = *(const uint2*)&w_csr[je0 * 64 + f4];
            uint2 wq1 = *(const uint2*)&w_csr[je1 * 64 + f4];
            uint2 xq0 = *(const uint2*)&x2[(long long)s0 * 64 + f4];
            uint2 xq1 = *(const uint2*)&x2[(long long)s1 * 64 + f4];
            a0 += bflo(xq0.x) * fsig(bflo(wq0.x)) + bflo(xq1.x) * fsig(bflo(wq1.x));
            a1 += bfhi(xq0.x) * fsig(bfhi(wq0.x)) + bfhi(xq1.x) * fsig(bfhi(wq1.x));
            a2 += bflo(xq0.y) * fsig(bflo(wq0.y)) + bflo(xq1.y) * fsig(bflo(wq1.y));
            a3 += bfhi(xq0.y) * fsig(bfhi(wq0.y)) + bfhi(xq1.y) * fsig(bfhi(wq1.y));
            if (FINAL) {
                uint2 hq0 = *(const uint2*)&h_e[je0 * 64 + f4];
                uint2 hq1 = *(const uint2*)&h_e[je1 * 64 + f4];
                long long e0 = eidx[je0], e1 = eidx[je1];
                *(float4*)&out_w[e0 * 64 + f4] = make_float4(
                    bflo(wq0.x) + silu(bflo(hq0.x) * km[f4]     + ka[f4]),
                    bfhi(wq0.x) + silu(bfhi(hq0.x) * km[f4 + 1] + ka[f4 + 1]),
                    bflo(wq0.y) + silu(bflo(hq0.y) * km[f4 + 2] + ka[f4 + 2]),
                    bfhi(wq0.y) + silu(bfhi(hq0.y) * km[f4 + 3] + ka[f4 + 3]));
                *(float4*)&out_w[e1 * 64 + f4] = make_float4(
                    bflo(wq1.x) + silu(bflo(hq1.x) * km[f4]     + ka[f4]),
                    bfhi(wq1.x) + silu(bfhi(hq1.x) * km[f4 + 1] + ka[f4 + 1]),
                    bflo(wq1.y) + silu(bflo(hq1.y) * km[f4 + 2] + ka[f4 + 2]),
                    bfhi(wq1.y) + silu(bfhi(hq1.y) * km[f4 + 3] + ka[f4 + 3]));
            }
        }
        for (; j + 1 < o1; j += 2) {        // one pair
            long long je0 = j + sub;
            int s0 = srcc[je0];
            uint2 wq0 = *(const uint2*)&w_csr[je0 * 64 + f4];
            uint2 xq0 = *(const uint2*)&x2[(long long)s0 * 64 + f4];
            a0 += bflo(xq0.x) * fsig(bflo(wq0.x));
            a1 += bfhi(xq0.x) * fsig(bfhi(wq0.x));
            a2 += bflo(xq0.y) * fsig(bflo(wq0.y));
            a3 += bfhi(xq0.y) * fsig(bfhi(wq0.y));
            if (FINAL) {
                uint2 hq0 = *(const uint2*)&h_e[je0 * 64 + f4];
                long long e0 = eidx[je0];
                *(float4*)&out_w[e0 * 64 + f4] = make_float4(
                    bflo(wq0.x) + silu(bflo(hq0.x) * km[f4]     + ka[f4]),
                    bfhi(wq0.x) + silu(bfhi(hq0.x) * km[f4 + 1] + ka[f4 + 1]),
                    bflo(wq0.y) + silu(bflo(hq0.y) * km[f4 + 2] + ka[f4 + 2]),
                    bfhi(wq0.y) + silu(bfhi(hq0.y) * km[f4 + 3] + ka[f4 + 3]));
            }
        }
        if (j < o1 && sub == 0) {           // odd tail, handled by sub 0
            long long je0 = j;
            int s0 = srcc[je0];
            uint2 wq0 = *(const uint2*)&w_csr[je0 * 64 + f4];
            uint2 xq0 = *(const uint2*)&x2[(long long)s0 * 64 + f4];
            a0 += bflo(xq0.x) * fsig(bflo(wq0.x));
            a1 += bfhi(xq0.x) * fsig(bfhi(wq0.x));
            a2 += bflo(xq0.y) * fsig(bflo(wq0.y));
            a3 += bfhi(xq0.y) * fsig(bfhi(wq0.y));
            if (FINAL) {
                uint2 hq0 = *(const uint2*)&h_e[je0 * 64 + f4];
                long long e0 = eidx[je0];
                *(float4*)&out_w[e0 * 64 + f4] = make_float4(
                    bflo(wq0.x) + silu(bflo(hq0.x) * km[f4]     + ka[f4]),
                    bfhi(wq0.x) + silu(bfhi(hq0.x) * km[f4 + 1] + ka[f4 + 1]),
                    bflo(wq0.y) + silu(bflo(hq0.y) * km[f4 + 2] + ka[f4 + 2]),
                    bfhi(wq0.y) + silu(bfhi(hq0.y) * km[f4 + 3] + ka[f4 + 3]));
            }
        }
        // combine sub halves (lane l <-> l^16 within same half-wave)
        a0 += __shfl_xor(a0, 16);
        a1 += __shfl_xor(a1, 16);
        a2 += __shfl_xor(a2, 16);
        a3 += __shfl_xor(a3, 16);
        float ic = 1.f / fmaxf((float)(o1 - o0), 1.f);
        uint2 xq = *(const uint2*)&x1[(long long)n * 64 + f4];
        h0 = bflo(xq.x) + a0 * ic;
        h1 = bfhi(xq.x) + a1 * ic;
        h2 = bflo(xq.y) + a2 * ic;
        h3 = bfhi(xq.y) + a3 * ic;
        if (sub == 0)
            *(float4*)&h_v[(long long)n * 64 + f4] = make_float4(h0, h1, h2, h3);
    }
    if (sub == 0)
        *(float4*)&red[hw * 68 + f4] = make_float4(h0, h1, h2, h3);
    __syncthreads();
    float* nst = nstats + (blockIdx.x & 7) * 128;
    if (tid < 64) {
        float s = 0.f;
        #pragma unroll
        for (int r = 0; r < 8; r++) s += red[r * 68 + tid];
        atomicAdd(&nst[tid], s);
    }
    __syncthreads();
    if (sub == 0)
        *(float4*)&red[hw * 68 + f4] = make_float4(h0 * h0, h1 * h1, h2 * h2, h3 * h3);
    __syncthreads();
    if (tid < 64) {
        float s = 0.f;
        #pragma unroll
        for (int r = 0; r < 8; r++) s += red[r * 68 + tid];
        atomicAdd(&nst[64 + tid], s);
    }
}

// ---------- finalize edge part: estats -> fin[128..256] ----------
__global__ void finalize_edge_kernel(const float* __restrict__ estats,
                                     const float* __restrict__ es, const float* __restrict__ eb,
                                     float* __restrict__ fin, float invE) {
    int c = threadIdx.x;
    float s = 0.f, q = 0.f;
    #pragma unroll
    for (int r = 0; r < 8; r++) { s += estats[r * 128 + c]; q += estats[r * 128 + 64 + c]; }
    float mean = s * invE;
    float var = q * invE - mean * mean;
    float kmul = rsqrtf(var + 1e-5f) * es[c];
    fin[128 + c] = kmul;
    fin[192 + c] = eb[c] - mean * kmul;
}

// ---------- finalize node part: nstats -> fin[0..128] ----------
__global__ void finalize_node_kernel(const float* __restrict__ nstats,
                                     const float* __restrict__ vs, const float* __restrict__ vb,
                                     float* __restrict__ fin, float invN) {
    int c = threadIdx.x;
    float s = 0.f, q = 0.f;
    #pragma unroll
    for (int r = 0; r < 8; r++) { s += nstats[r * 128 + c]; q += nstats[r * 128 + 64 + c]; }
    float mean = s * invN;
    float var = q * invN - mean * mean;
    float kmul = rsqrtf(var + 1e-5f) * vs[c];
    fin[c] = kmul;
    fin[64 + c] = vb[c] - mean * kmul;
}

// ---------- node BN apply (standalone, last layer only) ----------
__global__ __launch_bounds__(256)
void node_apply_kernel(const float4* __restrict__ hv4, const float4* __restrict__ xold4,
                       float4* __restrict__ out4, const float* __restrict__ fin, int total) {
    __shared__ float km[64], ka[64];
    if (threadIdx.x < 64) { km[threadIdx.x] = fin[threadIdx.x]; ka[threadIdx.x] = fin[64 + threadIdx.x]; }
    __syncthreads();
    int idx = blockIdx.x * 256 + threadIdx.x;
    if (idx >= total) return;
    int c0 = (idx & 15) * 4;
    float4 h = hv4[idx], xo = xold4[idx];
    float4 m = *(float4*)&km[c0], a = *(float4*)&ka[c0];
    float g0 = h.x * m.x + a.x, g1 = h.y * m.y + a.y, g2 = h.z * m.z + a.z, g3 = h.w * m.w + a.w;
    out4[idx] = make_float4(xo.x + silu(g0), xo.y + silu(g1),
                            xo.z + silu(g2), xo.w + silu(g3));
}

// ---------- launch ----------
extern "C" void kernel_launch(void* const* d_in, const int* in_sizes, int n_in,
                              void* d_out, int out_size, void* d_ws, size_t ws_size,
                              hipStream_t stream) {
    const float* x_in  = (const float*)d_in[0];
    const float* ea_in = (const float*)d_in[1];
    const int*   ei    = (const int*)d_in[2];
    const float* v_w   = (const float*)d_in[3];
    const float* v_b   = (const float*)d_in[4];
    const float* e_w   = (const float*)d_in[5];
    const float* e_b   = (const float*)d_in[6];
    const float* vbn_s = (const float*)d_in[7];
    const float* vbn_b = (const float*)d_in[8];
    const float* ebn_s = (const float*)d_in[9];
    const float* ebn_b = (const float*)d_in[10];

    const int Nn = in_sizes[0] / 64;
    const int E  = in_sizes[1] / 64;
    const int L  = in_sizes[3] / (4 * 64 * 64);

    const int* dst = ei;
    const int* src = ei + E;

    // workspace layout
    float* h_v    = (float*)d_ws;                       // [Nn][64] fp32
    float* nstats = h_v + (long long)Nn * 64;           // [L][8][128]
    float* estats = nstats + (long long)L * 1024;       // [L][8][128]
    float* fin    = estats + (long long)L * 1024;       // [4][64]
    __hip_bfloat16* xp0   = (__hip_bfloat16*)(fin + 256);      // [4][Nn][64]
    __hip_bfloat16* xp1   = xp0 + (long long)4 * Nn * 64;      // [4][Nn][64]
    __hip_bfloat16* h_e   = xp1 + (long long)4 * Nn * 64;      // [E][64] CSR (last layer only)
    __hip_bfloat16* w_csr = h_e + (long long)E * 64;           // [E][64] CSR
    short* vwp = (short*)(w_csr + (long long)E * 64);   // [L][4][4][2][64][8]
    short* ewp = vwp + (long long)L * 16384;            // [L][4][2][64][8]
    int* cnt  = (int*)(ewp + (long long)L * 4096);      // [Nn]
    int* off  = cnt + Nn;                               // [Nn+1]
    int* eidx = off + Nn + 1;                           // [E]
    int* dstc = eidx + E;                               // [E]
    int* srcc = dstc + E;                               // [E]
    int* bsum = srcc + E;                               // [64]

    size_t needed = ((size_t)Nn * 64 + (size_t)L * 2048 + 256) * 4 +
                    ((size_t)8 * Nn * 64 + (size_t)2 * E * 64 + (size_t)L * 20480) * 2 +
                    ((size_t)2 * Nn + 1 + (size_t)3 * E + 64) * 4;
    if (ws_size < needed) return;

    float* out_x = (float*)d_out;
    float* out_w = out_x + (long long)Nn * 64;

    // CSR build + zero stats + pack weights (once per call)
    const int nb = (Nn + 1023) / 1024;
    zero_int_kernel<<<64, 256, 0, stream>>>(cnt, Nn);
    zero_int_kernel<<<8, 256, 0, stream>>>((int*)nstats, L * 2048);
    count_kernel<<<(E + 255) / 256, 256, 0, stream>>>(dst, cnt, E);
    scan_block_kernel<<<nb, 1024, 0, stream>>>(cnt, off, bsum, Nn);
    scan_tops_kernel<<<1, 64, 0, stream>>>(bsum, nb);
    scan_add_kernel<<<nb, 1024, 0, stream>>>(off, bsum, Nn);
    fill_csr_kernel<<<(E + 255) / 256, 256, 0, stream>>>(dst, src, off, cnt, eidx, dstc, srcc, E);
    pack_kernel<<<(L * 2560 + 255) / 256, 256, 0, stream>>>(v_w, e_w, vwp, ewp, L);

    for (int l = 0; l < L; l++) {
        bool first = (l == 0);
        bool last = (l == L - 1);
        float* nst = nstats + (long long)l * 1024;
        float* est = estats + (long long)l * 1024;
        __hip_bfloat16* xp_cur  = (l & 1) ? xp1 : xp0;
        __hip_bfloat16* xp_prev = (l & 1) ? xp0 : xp1;
        const __hip_bfloat16* x1 = xp_cur;
        const __hip_bfloat16* x2 = xp_cur + (long long)Nn * 64;
        const __hip_bfloat16* x3 = xp_cur + (long long)2 * Nn * 64;
        const __hip_bfloat16* x4 = xp_cur + (long long)3 * Nn * 64;
        const __hip_bfloat16* x3p = xp_prev + (long long)2 * Nn * 64;
        const __hip_bfloat16* x4p = xp_prev + (long long)3 * Nn * 64;

        // node projections -> xp_cur; l>=1 fuses previous layer's residual apply
        const float* xold = (l <= 1) ? x_in : out_x;
        if (first)
            node_gemm_mfma<false><<<(Nn + 63) / 64, 256, 0, stream>>>(
                x_in, h_v, out_x, fin, vwp + (long long)l * 16384, v_b + l * 256, xp_cur, Nn);
        else
            node_gemm_mfma<true><<<(Nn + 63) / 64, 256, 0, stream>>>(
                xold, h_v, out_x, fin, vwp + (long long)l * 16384, v_b + l * 256, xp_cur, Nn);

        // edge GEMM: stage w + (recompute h_prev + fused update) + stats (+ h_e if last)
        const short* ewp_c = ewp + (long long)l * 4096;
        const short* ewp_pv = (l > 0) ? ewp + (long long)(l - 1) * 4096 : ewp_c;
        const float* eb_c = e_b + l * 64;
        const float* eb_pv = (l > 0) ? e_b + (l - 1) * 64 : eb_c;
        if (first && !last)
            edge_gemm_mfma<true, false><<<E / 64, 256, 0, stream>>>(
                ea_in, eidx, w_csr, h_e, fin, ewp_pv, eb_pv, ewp_c, eb_c,
                x3p, x4p, x3, x4, dstc, srcc, est);
        else if (first && last)
            edge_gemm_mfma<true, true><<<E / 64, 256, 0, stream>>>(
                ea_in, eidx, w_csr, h_e, fin, ewp_pv, eb_pv, ewp_c, eb_c,
                x3p, x4p, x3, x4, dstc, srcc, est);
        else if (!first && !last)
            edge_gemm_mfma<false, false><<<E / 64, 256, 0, stream>>>(
                ea_in, eidx, w_csr, h_e, fin, ewp_pv, eb_pv, ewp_c, eb_c,
                x3p, x4p, x3, x4, dstc, srcc, est);
        else
            edge_gemm_mfma<false, true><<<E / 64, 256, 0, stream>>>(
                ea_in, eidx, w_csr, h_e, fin, ewp_pv, eb_pv, ewp_c, eb_c,
                x3p, x4p, x3, x4, dstc, srcc, est);

        // fold edge BN affine -> fin[128..256]
        finalize_edge_kernel<<<1, 64, 0, stream>>>(
            est, ebn_s + l * 64, ebn_b + l * 64, fin, 1.f / (float)E);

        // aggregation + node stats (+ out_w emission on last layer)
        if (last)
            node_finish_kernel<true><<<(Nn + 7) / 8, 256, 0, stream>>>(
                w_csr, srcc, x2, x1, off, h_v, nst, h_e, eidx, out_w, fin, Nn);
        else
            node_finish_kernel<false><<<(Nn + 7) / 8, 256, 0, stream>>>(
                w_csr, srcc, x2, x1, off, h_v, nst, h_e, eidx, out_w, fin, Nn);

        // fold node BN affine -> fin[0..128]
        finalize_node_kernel<<<1, 64, 0, stream>>>(
            nst, vbn_s + l * 64, vbn_b + l * 64, fin, 1.f / (float)Nn);

        // standalone apply only for the last layer
        if (last) {
            const float* xo_last = (L == 1) ? x_in : out_x;
            node_apply_kernel<<<(Nn * 16 + 255) / 256, 256, 0, stream>>>(
                (const float4*)h_v, (const float4*)xo_last, (float4*)out_x, fin, Nn * 16);
        }
    }
}